// Round 4
// baseline (389.872 us; speedup 1.0000x reference)
//
#include <hip/hip_runtime.h>

#define N_NODES 100000
#define N_EDGES 1250000
#define D 64

typedef long long ll;

// ---------- CSR build: counting sort of edges by dst ----------

__global__ void hist_kernel(const int* __restrict__ dst, int* __restrict__ cnt) {
    int e = blockIdx.x * 256 + threadIdx.x;
    if (e < N_EDGES) atomicAdd(&cnt[dst[e]], 1);
}

// per-block (256-elem) exclusive scan of cnt in place; block totals to bsum
__global__ void scanA_kernel(int* __restrict__ cnt, int* __restrict__ bsum) {
    __shared__ int s[256];
    int tid = threadIdx.x, gid = blockIdx.x * 256 + tid;
    int x = (gid < N_NODES) ? cnt[gid] : 0;
    s[tid] = x;
    __syncthreads();
    for (int off = 1; off < 256; off <<= 1) {
        int v = (tid >= off) ? s[tid - off] : 0;
        __syncthreads();
        s[tid] += v;
        __syncthreads();
    }
    if (gid < N_NODES) cnt[gid] = s[tid] - x;   // exclusive within block
    if (tid == 255) bsum[blockIdx.x] = s[255];  // block total
}

// single-block exclusive scan of the nb block totals
__global__ void scanB_kernel(const int* __restrict__ bsum, int* __restrict__ boff, int nb) {
    __shared__ int s[512];
    int tid = threadIdx.x;
    int x = (tid < nb) ? bsum[tid] : 0;
    s[tid] = x;
    __syncthreads();
    for (int off = 1; off < 512; off <<= 1) {
        int v = (tid >= off) ? s[tid - off] : 0;
        __syncthreads();
        s[tid] += v;
        __syncthreads();
    }
    if (tid < nb) boff[tid] = s[tid] - x;
}

// add block offsets -> cnt becomes CSR offsets; duplicate into cursor
__global__ void scanC_kernel(int* __restrict__ cnt, const int* __restrict__ boff,
                             int* __restrict__ cursor) {
    int gid = blockIdx.x * 256 + threadIdx.x;
    if (gid < N_NODES) {
        int v = cnt[gid] + boff[blockIdx.x];
        cnt[gid] = v;
        cursor[gid] = v;
    }
}

__global__ void reorder_kernel(const int* __restrict__ src, const int* __restrict__ dst,
                               int* __restrict__ cursor, int* __restrict__ srt) {
    int e = blockIdx.x * 256 + threadIdx.x;
    if (e < N_EDGES) {
        int p = atomicAdd(&cursor[dst[e]], 1);
        srt[p] = src[e];
    }
}

// ---------- fused pull + linear ----------
// One wave per node (grid-stride, 8192 waves = full machine). Lane j
// accumulates agg[n][j] via an 8-wide predicated gather batch. srt is padded
// with 8 zero entries so no index clamping is needed (id 0 is a valid row;
// predication zeroes the contribution). Then the row round-trips through a
// per-wave LDS buffer (wave-synchronous) and is consumed as broadcast float4
// against W1 row `lane` held in 64 VGPRs:
//   out[n][j] = b1[j] + sum_k row[k] * W1[j*64+k]
#define NBLK 2048
__global__ __launch_bounds__(256) void fused_layer(const float* __restrict__ h,
                                                   const int* __restrict__ offs,
                                                   const int* __restrict__ srt,
                                                   const float* __restrict__ W1,
                                                   const float* __restrict__ b1,
                                                   float* __restrict__ out) {
    __shared__ __align__(16) float rowbuf[4][64];
    const int tid  = threadIdx.x;
    const int lane = tid & 63;
    const int wid  = tid >> 6;
    const int gw   = blockIdx.x * 4 + wid;   // global wave id
    const int GW   = NBLK * 4;               // total waves

    // W1 row `lane` in registers: Wreg[i] = W1[lane*64 + 4i .. +4)
    float4 Wreg[16];
    const float4* wrow = (const float4*)(W1 + lane * D);
#pragma unroll
    for (int i = 0; i < 16; ++i) Wreg[i] = wrow[i];
    const float bj = b1[lane];

    for (int n = gw; n < N_NODES; n += GW) {
        const int beg = offs[n];
        const int end = (n == N_NODES - 1) ? N_EDGES : offs[n + 1];

        float a0 = 0.f, a1 = 0.f, a2 = 0.f, a3 = 0.f;
        for (int e = beg; e < end; e += 8) {
            // srt has an 8-entry zero pad: unclamped reads are always in-bounds
            int s0 = srt[e],     s1 = srt[e + 1], s2 = srt[e + 2], s3 = srt[e + 3];
            int s4 = srt[e + 4], s5 = srt[e + 5], s6 = srt[e + 6], s7 = srt[e + 7];
            float g0 = h[(ll)s0 * D + lane];
            float g1 = h[(ll)s1 * D + lane];
            float g2 = h[(ll)s2 * D + lane];
            float g3 = h[(ll)s3 * D + lane];
            float g4 = h[(ll)s4 * D + lane];
            float g5 = h[(ll)s5 * D + lane];
            float g6 = h[(ll)s6 * D + lane];
            float g7 = h[(ll)s7 * D + lane];
            a0 += g0;
            a1 += (e + 1 < end) ? g1 : 0.f;
            a2 += (e + 2 < end) ? g2 : 0.f;
            a3 += (e + 3 < end) ? g3 : 0.f;
            a0 += (e + 4 < end) ? g4 : 0.f;
            a1 += (e + 5 < end) ? g5 : 0.f;
            a2 += (e + 6 < end) ? g6 : 0.f;
            a3 += (e + 7 < end) ? g7 : 0.f;
        }
        const float acc = (a0 + a1) + (a2 + a3);

        // wave-synchronous LDS transpose: write lane value, read back as
        // broadcast float4
        rowbuf[wid][lane] = acc;
        float o = bj;
        const float4* rb = (const float4*)rowbuf[wid];
#pragma unroll
        for (int k4 = 0; k4 < 16; ++k4) {
            float4 r = rb[k4];     // broadcast ds_read_b128
            o += r.x * Wreg[k4].x + r.y * Wreg[k4].y
               + r.z * Wreg[k4].z + r.w * Wreg[k4].w;
        }
        out[(ll)n * D + lane] = o;
    }
}

extern "C" void kernel_launch(void* const* d_in, const int* in_sizes, int n_in,
                              void* d_out, int out_size, void* d_ws, size_t ws_size,
                              hipStream_t stream) {
    const float* x  = (const float*)d_in[0];   // [N, D]
    const int* edge = (const int*)d_in[1];     // [2, E]: src row then dst row
    const float* W1 = (const float*)d_in[2];   // [D, D]
    const float* b1 = (const float*)d_in[3];   // [D]

    const int* src = edge;
    const int* dst = edge + N_EDGES;

    float* out = (float*)d_out;                    // output 0: [N, D]
    float* hid = (float*)d_out + (ll)N_NODES * D;  // output 1: [N, D]

    // workspace layout (~5.9 MB)
    char* ws = (char*)d_ws;
    int* cnt    = (int*)ws;  ws += ((size_t)N_NODES * 4 + 255) & ~255ull;  // -> CSR offsets
    int* cursor = (int*)ws;  ws += ((size_t)N_NODES * 4 + 255) & ~255ull;
    int* bsum   = (int*)ws;  ws += 4096;
    int* boff   = (int*)ws;  ws += 4096;
    int* srt    = (int*)ws;                    // [E + 8] src ids sorted by dst (+zero pad)

    const int nbA = (N_NODES + 255) / 256;   // 391
    const int nbE = (N_EDGES + 255) / 256;   // 4883

    // ---- build CSR (once; reused by both layers) ----
    hipMemsetAsync(cnt, 0, (size_t)N_NODES * 4, stream);
    hipMemsetAsync(srt + N_EDGES, 0, 8 * sizeof(int), stream);  // zero pad (ws is poisoned)
    hist_kernel<<<nbE, 256, 0, stream>>>(dst, cnt);
    scanA_kernel<<<nbA, 256, 0, stream>>>(cnt, bsum);
    scanB_kernel<<<1, 512, 0, stream>>>(bsum, boff, nbA);
    scanC_kernel<<<nbA, 256, 0, stream>>>(cnt, boff, cursor);
    reorder_kernel<<<nbE, 256, 0, stream>>>(src, dst, cursor, srt);

    // ---- layer 1: hid = segsum(x) @ W1^T + b1 ----
    fused_layer<<<NBLK, 256, 0, stream>>>(x, cnt, srt, W1, b1, hid);
    // ---- layer 2: out = segsum(hid) @ W1^T + b1 ----
    fused_layer<<<NBLK, 256, 0, stream>>>(hid, cnt, srt, W1, b1, out);
}

// Round 5
// 273.840 us; speedup vs baseline: 1.4237x; 1.4237x over previous
//
#include <hip/hip_runtime.h>

#define N_NODES 100000
#define N_EDGES 1250000
#define D 64

#define BSHIFT 9
#define BUCKETS 196          // ceil(100000 / 512)
#define CAP 8192             // srtTmp capacity per bucket (mean 6378, +22 sigma)
#define CHUNK 4096           // edges per bucketA block
#define PA_BLOCKS ((N_EDGES + CHUNK - 1) / CHUNK)   // 306
#define LCAP 64              // LDS list capacity per bucket per chunk (mean 21)

typedef long long ll;

// ---------- init: cursor[b] = b*CAP; zero-pad srt tail ----------
__global__ void init_kernel(int* __restrict__ cursor, int* __restrict__ srt) {
    int t = threadIdx.x;
    if (t < BUCKETS) cursor[t] = t * CAP;
    if (t < 8) srt[N_EDGES + t] = 0;
}

// ---------- pass A: bin edges into 196 coarse buckets, coalesced flushes ----------
__global__ __launch_bounds__(256) void bucketA_kernel(const int* __restrict__ src,
                                                      const int* __restrict__ dst,
                                                      int* __restrict__ cursor,
                                                      int* __restrict__ tmp) {
    __shared__ int lcnt[BUCKETS];
    __shared__ int list[BUCKETS * LCAP];   // ~50 KB
    int tid = threadIdx.x;
    for (int b = tid; b < BUCKETS; b += 256) lcnt[b] = 0;
    __syncthreads();

    int base = blockIdx.x * CHUNK;
    int nE = min(CHUNK, N_EDGES - base);
    for (int i = tid; i < nE; i += 256) {
        int e = base + i;
        int s = src[e], d = dst[e];
        int b = d >> BSHIFT;
        int p = atomicAdd(&lcnt[b], 1);            // LDS atomic, cheap
        list[b * LCAP + p] = s | ((d & 511) << 17); // src:17b, dstLow:9b
    }
    __syncthreads();

    // one global atomic per (block, bucket); flush run is contiguous
    for (int b = tid; b < BUCKETS; b += 256) {
        int c = lcnt[b];
        if (c > 0) {
            int gb = atomicAdd(&cursor[b], c);
            for (int k = 0; k < c; ++k) tmp[gb + k] = list[b * LCAP + k];
        }
    }
}

// ---------- tiny scan: bucket bases from cursor counts ----------
__global__ void scanSmall_kernel(const int* __restrict__ cursor, int* __restrict__ bbase) {
    __shared__ int s[256];
    int tid = threadIdx.x;
    int x = (tid < BUCKETS) ? (cursor[tid] - tid * CAP) : 0;
    s[tid] = x;
    __syncthreads();
    for (int off = 1; off < 256; off <<= 1) {
        int v = (tid >= off) ? s[tid - off] : 0;
        __syncthreads();
        s[tid] += v;
        __syncthreads();
    }
    if (tid < BUCKETS) bbase[tid] = s[tid] - x;   // exclusive
}

// ---------- pass B: per-bucket local sort -> final srt + offs ----------
// One block (512 threads) per bucket. LDS hist over 512 local nodes, LDS scan,
// scatter into the bucket's 25KB window of srt (L2-resident), write offs.
__global__ __launch_bounds__(512) void bucketB_kernel(const int* __restrict__ cursor,
                                                      const int* __restrict__ bbase,
                                                      const int* __restrict__ tmp,
                                                      int* __restrict__ srt,
                                                      int* __restrict__ offs) {
    __shared__ int hist[512];
    __shared__ int s[512];
    __shared__ int cur[512];
    int b = blockIdx.x, tid = threadIdx.x;
    int cbase = b * CAP;
    int cnt = cursor[b] - cbase;
    int gbase = bbase[b];

    hist[tid] = 0;
    __syncthreads();
    for (int i = tid; i < cnt; i += 512) {
        int ln = tmp[cbase + i] >> 17;
        atomicAdd(&hist[ln], 1);          // LDS atomic, avg 12.5/node
    }
    __syncthreads();

    // inclusive Hillis-Steele over 512 -> exclusive
    int x = hist[tid];
    s[tid] = x;
    __syncthreads();
    for (int off = 1; off < 512; off <<= 1) {
        int v = (tid >= off) ? s[tid - off] : 0;
        __syncthreads();
        s[tid] += v;
        __syncthreads();
    }
    int excl = s[tid] - x;
    cur[tid] = excl;

    int node0 = b << BSHIFT;
    int nloc = min(512, N_NODES - node0);
    if (tid < nloc) offs[node0 + tid] = gbase + excl;   // coalesced
    __syncthreads();

    for (int i = tid; i < cnt; i += 512) {
        int v = tmp[cbase + i];            // L2-hot (second read)
        int ln = v >> 17;
        int p = atomicAdd(&cur[ln], 1);
        srt[gbase + p] = v & 0x1FFFF;      // random within 25KB window, L2-buffered
    }
}

// ---------- fused pull + linear (unchanged from round 4) ----------
#define NBLK 2048
__global__ __launch_bounds__(256) void fused_layer(const float* __restrict__ h,
                                                   const int* __restrict__ offs,
                                                   const int* __restrict__ srt,
                                                   const float* __restrict__ W1,
                                                   const float* __restrict__ b1,
                                                   float* __restrict__ out) {
    __shared__ __align__(16) float rowbuf[4][64];
    const int tid  = threadIdx.x;
    const int lane = tid & 63;
    const int wid  = tid >> 6;
    const int gw   = blockIdx.x * 4 + wid;
    const int GW   = NBLK * 4;

    float4 Wreg[16];
    const float4* wrow = (const float4*)(W1 + lane * D);
#pragma unroll
    for (int i = 0; i < 16; ++i) Wreg[i] = wrow[i];
    const float bj = b1[lane];

    for (int n = gw; n < N_NODES; n += GW) {
        const int beg = offs[n];
        const int end = (n == N_NODES - 1) ? N_EDGES : offs[n + 1];

        float a0 = 0.f, a1 = 0.f, a2 = 0.f, a3 = 0.f;
        for (int e = beg; e < end; e += 8) {
            int s0 = srt[e],     s1 = srt[e + 1], s2 = srt[e + 2], s3 = srt[e + 3];
            int s4 = srt[e + 4], s5 = srt[e + 5], s6 = srt[e + 6], s7 = srt[e + 7];
            float g0 = h[(ll)s0 * D + lane];
            float g1 = h[(ll)s1 * D + lane];
            float g2 = h[(ll)s2 * D + lane];
            float g3 = h[(ll)s3 * D + lane];
            float g4 = h[(ll)s4 * D + lane];
            float g5 = h[(ll)s5 * D + lane];
            float g6 = h[(ll)s6 * D + lane];
            float g7 = h[(ll)s7 * D + lane];
            a0 += g0;
            a1 += (e + 1 < end) ? g1 : 0.f;
            a2 += (e + 2 < end) ? g2 : 0.f;
            a3 += (e + 3 < end) ? g3 : 0.f;
            a0 += (e + 4 < end) ? g4 : 0.f;
            a1 += (e + 5 < end) ? g5 : 0.f;
            a2 += (e + 6 < end) ? g6 : 0.f;
            a3 += (e + 7 < end) ? g7 : 0.f;
        }
        const float acc = (a0 + a1) + (a2 + a3);

        rowbuf[wid][lane] = acc;
        float o = bj;
        const float4* rb = (const float4*)rowbuf[wid];
#pragma unroll
        for (int k4 = 0; k4 < 16; ++k4) {
            float4 r = rb[k4];
            o += r.x * Wreg[k4].x + r.y * Wreg[k4].y
               + r.z * Wreg[k4].z + r.w * Wreg[k4].w;
        }
        out[(ll)n * D + lane] = o;
    }
}

extern "C" void kernel_launch(void* const* d_in, const int* in_sizes, int n_in,
                              void* d_out, int out_size, void* d_ws, size_t ws_size,
                              hipStream_t stream) {
    const float* x  = (const float*)d_in[0];   // [N, D]
    const int* edge = (const int*)d_in[1];     // [2, E]: src row then dst row
    const float* W1 = (const float*)d_in[2];   // [D, D]
    const float* b1 = (const float*)d_in[3];   // [D]

    const int* src = edge;
    const int* dst = edge + N_EDGES;

    float* out = (float*)d_out;                    // output 0: [N, D]
    float* hid = (float*)d_out + (ll)N_NODES * D;  // output 1: [N, D]

    // workspace layout (~12 MB; >=25.6 MB proven available in round 1)
    char* ws = (char*)d_ws;
    int* cursor = (int*)ws;  ws += 1024;                                   // [196]
    int* bbase  = (int*)ws;  ws += 1024;                                   // [196]
    int* offs   = (int*)ws;  ws += ((size_t)N_NODES * 4 + 255) & ~255ull;  // [N]
    int* srt    = (int*)ws;  ws += ((size_t)(N_EDGES + 8) * 4 + 255) & ~255ull;  // [E+8]
    int* tmp    = (int*)ws;                                                // [196*CAP]

    // ---- build CSR via two-pass bucket sort (once; reused by both layers) ----
    init_kernel<<<1, 256, 0, stream>>>(cursor, srt);
    bucketA_kernel<<<PA_BLOCKS, 256, 0, stream>>>(src, dst, cursor, tmp);
    scanSmall_kernel<<<1, 256, 0, stream>>>(cursor, bbase);
    bucketB_kernel<<<BUCKETS, 512, 0, stream>>>(cursor, bbase, tmp, srt, offs);

    // ---- layer 1: hid = segsum(x) @ W1^T + b1 ----
    fused_layer<<<NBLK, 256, 0, stream>>>(x, offs, srt, W1, b1, hid);
    // ---- layer 2: out = segsum(hid) @ W1^T + b1 ----
    fused_layer<<<NBLK, 256, 0, stream>>>(hid, offs, srt, W1, b1, out);
}